// Round 1
// 462.292 us; speedup vs baseline: 1.0641x; 1.0641x over previous
//
#include <hip/hip_runtime.h>
#include <hip/hip_bf16.h>
#include <cstdio>
#include <cstdint>

#define TNUM 2048
#define DDIM 768
#define HDIM 3072
#define ENUM 8

// counted vmcnt wait (keeps younger prefetch loads in flight across barriers)
#define WAITVM(N) asm volatile("s_waitcnt vmcnt(" #N ")" ::: "memory")
// compiler-level memory fence: stops LDS reads from being scheduled across a raw s_barrier
#define MEMFENCE() asm volatile("" ::: "memory")

typedef __attribute__((ext_vector_type(8))) __bf16 bf16x8;
typedef __attribute__((ext_vector_type(4))) float f32x4;
typedef __attribute__((ext_vector_type(8))) unsigned short ushort8_t;

__device__ __forceinline__ unsigned short f2bf(float f) {
    __bf16 h = (__bf16)f;            // RNE
    unsigned short u;
    __builtin_memcpy(&u, &h, 2);
    return u;
}

// async global->LDS, 16B per lane; LDS dest = wave-uniform base + lane*16
__device__ __forceinline__ void async_cp16(const unsigned short* g, unsigned short* l) {
    __builtin_amdgcn_global_load_lds((const __attribute__((address_space(1))) void*)g,
                                     (__attribute__((address_space(3))) void*)l,
                                     16, 0, 0);
}

// ---------------- cast x -> bf16 ----------------
__global__ void cast_x_kernel(const float* __restrict__ x, unsigned short* __restrict__ xb) {
    int i = (blockIdx.x * 256 + threadIdx.x) * 8;
    float4 a = *(const float4*)(x + i);
    float4 b = *(const float4*)(x + i + 4);
    ushort4 lo = make_ushort4(f2bf(a.x), f2bf(a.y), f2bf(a.z), f2bf(a.w));
    ushort4 hi = make_ushort4(f2bf(b.x), f2bf(b.y), f2bf(b.z), f2bf(b.w));
    *(ushort4*)(xb + i) = lo;
    *(ushort4*)(xb + i + 4) = hi;
}

// ---------------- transpose + cast weights to bf16 [n][k] ----------------
// 128x128 tiles. LDS tile is word-granular: column c of the input (= output row)
// occupies words [c*68, c*68+64); word (c, rp) packs input rows {2rp, 2rp+1} as bf16.
// Row pairing is done in-register via shfl_xor(32) (partner holds r^1, same columns),
// so writes are 2x ds_write_b32 instead of 4x ds_write_b16.
// Run swizzle: logical (q=rp>>2, k=rp&3) stored at 4*((q + 3*(c>>2))&15) + ((k + (c>>2))&3)
// -> write conflicts drop from 32-way (old layout) to 4-way; reads stay ds_read_b128
// with a wave-uniform register rotate to undo the k-scramble.
__global__ __launch_bounds__(256)
void transw_kernel(const float* __restrict__ W1, const float* __restrict__ W2,
                   const float* __restrict__ Ws1, const float* __restrict__ Ws2,
                   unsigned short* __restrict__ W1t, unsigned short* __restrict__ W2t,
                   unsigned short* __restrict__ Ws1t, unsigned short* __restrict__ Ws2t) {
    int z = blockIdx.z;
    const float* in; unsigned short* out; int R, C;
    if (z < 8)       { in = W1 + (size_t)z * DDIM * HDIM; out = W1t + (size_t)z * HDIM * DDIM; R = DDIM; C = HDIM; }
    else if (z < 16) { int e = z - 8; in = W2 + (size_t)e * HDIM * DDIM; out = W2t + (size_t)e * DDIM * HDIM; R = HDIM; C = DDIM; }
    else if (z == 16){ in = Ws1; out = Ws1t; R = DDIM; C = HDIM; }
    else             { in = Ws2; out = Ws2t; R = HDIM; C = DDIM; }
    int nx = C / 128;
    int c0 = (blockIdx.x % nx) * 128, r0 = (blockIdx.x / nx) * 128;
    __shared__ __align__(16) unsigned int tileT32[128 * 68];   // 34816 B
    int tid = threadIdx.x;
    int l15 = tid & 15;
    int g = tid >> 4;
    int par = (g >> 1) & 1;        // parity of this thread's input row
    int hf = g & 1;
    int cb = hf * 64 + l15 * 4;
    #pragma unroll
    for (int p = 0; p < 16; p++) {
        int unit = p * 16 + g;
        int r = unit >> 1;
        float4 v = *(const float4*)(in + (size_t)(r0 + r) * C + c0 + cb);
        unsigned int m01 = (unsigned int)f2bf(v.x) | ((unsigned int)f2bf(v.y) << 16);
        unsigned int m23 = (unsigned int)f2bf(v.z) | ((unsigned int)f2bf(v.w) << 16);
        unsigned int o01 = __shfl_xor(m01, 32);   // partner (lane^32) holds row r^1, same cols
        unsigned int o23 = __shfl_xor(m23, 32);
        // par==0: write cols cb+0,cb+1 (lo=even row=mine, hi=odd row=partner)
        // par==1: write cols cb+2,cb+3 (lo=even row=partner, hi=odd row=mine)
        unsigned int wA = par ? ((o23 & 0xffffu) | (m23 << 16))
                              : ((m01 & 0xffffu) | (o01 << 16));
        unsigned int wB = par ? ((o23 >> 16) | (m23 & 0xffff0000u))
                              : ((m01 >> 16) | (o01 & 0xffff0000u));
        int ca = cb + par * 2;
        int rp = unit >> 2;                       // pair index r>>1
        int cq = ca >> 2;                         // same for ca and ca+1
        int woff = 4 * (((rp >> 2) + 3 * cq) & 15) + (((rp & 3) + cq) & 3);
        tileT32[ca * 68 + woff] = wA;
        tileT32[(ca + 1) * 68 + woff] = wB;
    }
    __syncthreads();
    #pragma unroll
    for (int p = 0; p < 8; p++) {
        int cc = p * 16 + g;                      // output row (= input col)
        int cqp = cc >> 2;                        // wave-uniform
        const uint4 W = *(const uint4*)&tileT32[cc * 68 + 4 * ((l15 + 3 * cqp) & 15)];
        unsigned int a0 = W.x, a1 = W.y, a2 = W.z, a3 = W.w;
        int rsel = cqp & 3;                       // wave-uniform rotate to undo k-scramble
        if (rsel & 1) { unsigned int t = a0; a0 = a1; a1 = a2; a2 = a3; a3 = t; }
        if (rsel & 2) { unsigned int t0 = a0, t1 = a1; a0 = a2; a1 = a3; a2 = t0; a3 = t1; }
        uint4 ov; ov.x = a0; ov.y = a1; ov.z = a2; ov.w = a3;
        *(uint4*)(out + (size_t)(c0 + cc) * R + r0 + l15 * 8) = ov;   // rows l15*8..+8 in order
    }
}

// ---------------- router: one wave per token ----------------
__global__ void router_kernel(const float* __restrict__ x, const float* __restrict__ noise,
                              const float* __restrict__ Wr, const float* __restrict__ br,
                              int* __restrict__ counts, int* __restrict__ list,
                              int* __restrict__ inv, float* __restrict__ tokp) {
    int lane = threadIdx.x & 63;
    int t = blockIdx.x * 4 + (threadIdx.x >> 6);
    float acc[8];
    #pragma unroll
    for (int e = 0; e < 8; e++) acc[e] = 0.f;
    #pragma unroll
    for (int i = 0; i < 12; i++) {
        int d = i * 64 + lane;
        float xv = x[t * DDIM + d];
        float4 w0 = *(const float4*)(Wr + d * 8);
        float4 w1 = *(const float4*)(Wr + d * 8 + 4);
        acc[0] += xv * w0.x; acc[1] += xv * w0.y; acc[2] += xv * w0.z; acc[3] += xv * w0.w;
        acc[4] += xv * w1.x; acc[5] += xv * w1.y; acc[6] += xv * w1.z; acc[7] += xv * w1.w;
    }
    #pragma unroll
    for (int e = 0; e < 8; e++) {
        #pragma unroll
        for (int off2 = 32; off2 >= 1; off2 >>= 1)
            acc[e] += __shfl_xor(acc[e], off2, 64);
    }
    if (lane == 0) {
        float lg[8];
        #pragma unroll
        for (int e = 0; e < 8; e++) lg[e] = acc[e] + br[e] + 0.1f * noise[t * 8 + e];
        int e0 = 0;
        #pragma unroll
        for (int e = 1; e < 8; e++) if (lg[e] > lg[e0]) e0 = e;
        int e1 = -1;
        #pragma unroll
        for (int e = 0; e < 8; e++) if (e != e0 && (e1 < 0 || lg[e] > lg[e1])) e1 = e;
        float m = fmaxf(lg[e0], lg[e1]);
        float p0 = expf(lg[e0] - m), p1 = expf(lg[e1] - m);
        float inv_s = 1.f / (p0 + p1);
        int s0 = atomicAdd(&counts[e0], 1);
        list[e0 * TNUM + s0] = t;
        int s1 = atomicAdd(&counts[e1], 1);
        list[e1 * TNUM + s1] = t;
        inv[t * 2 + 0] = (e0 << 16) | s0;
        inv[t * 2 + 1] = (e1 << 16) | s1;
        tokp[t * 2 + 0] = p0 * inv_s;
        tokp[t * 2 + 1] = p1 * inv_s;
    }
}

// ---------------- prefix offsets + mixing scalars ----------------
__global__ void finalize_kernel(const int* __restrict__ counts, int* __restrict__ offs,
                                const float* __restrict__ alpha, const float* __restrict__ beta,
                                float* __restrict__ scal) {
    int s = 0;
    for (int e = 0; e < 8; e++) { offs[e] = s; s += counts[e]; }
    offs[8] = s;   // == 4096
    float a = alpha[0], b = beta[0];
    float m = fmaxf(a, b);
    float ea = expf(a - m), eb = expf(b - m);
    float inv = 1.f / (ea + eb);
    scal[0] = ea * inv;   // shared expert weight
    scal[1] = eb * inv;   // moe weight
}

// BK=32 LDS tile layout (16B group = one (row, k-oct)):
//   group G = rc*64 + quad*16 + l15  ->  (row = rc*16+l15, k = quad*8)
// Pipeline: 3 LDS buffers, prefetch depth 2. Raw s_barrier + counted vmcnt:
//   at top of step kt, wait vmcnt(L) (L = loads/tile/wave) -> tile kt complete,
//   tile kt+1 still in flight; after barrier issue tile kt+2. Loads get ~2 full
//   K-steps to cover L2/HBM latency instead of being drained every step.
// Grids: x=8 (XCD slot), z=job layer, y=48 compact tiles; data-dependent
// m-tile counts handled by an in-kernel mt-stride loop (no early-exit storm).

// ---------------- GEMM layer 1: h = leaky(x @ W1[e] + b1[e]) ----------------
// BM=128, BN=128, BK=32. 24 jobs:
//   j<16: expert e=j>>1, n-half nh=j&1 (A 0.75MB + B 2.25MB in one XCD L2)
//   j>=16: shared slab ms=q>>1 (512 rows) x nh=q&1  -> all 8 XCDs balanced
__global__ __launch_bounds__(256, 3)
void ffn1_kernel(const unsigned short* __restrict__ xb,
                 const unsigned short* __restrict__ W1t,   // [8][3072][768]
                 const unsigned short* __restrict__ Ws1t,  // [3072][768]
                 const float* __restrict__ b1, const float* __restrict__ bs1,
                 const int* __restrict__ counts, const int* __restrict__ offs,
                 const int* __restrict__ list,
                 unsigned short* __restrict__ hbuf) {      // [6144][3072]
    int j = blockIdx.z * 8 + blockIdx.x;    // 0..23
    int y = blockIdx.y;                     // 0..47
    int mt0 = y / 12, ntl = y % 12;         // mt0 0..3, ntl 0..11
    int cnt, hbase, n0, mbase, ntiles;
    const unsigned short* Bmat;
    const float* bias;
    const int* lst = nullptr;
    if (j < 16) {
        int e = j >> 1, nh = j & 1;
        cnt = counts[e];
        ntiles = (cnt + 127) >> 7;
        mbase = 0;
        hbase = offs[e];
        n0 = nh * 1536 + ntl * 128;
        Bmat = W1t + (size_t)e * HDIM * DDIM;
        bias = b1 + e * HDIM;
        lst = list + e * TNUM;
    } else {
        int q = j - 16;                     // 0..7
        int ms = q >> 1, nh = q & 1;
        mbase = ms * 512;
        ntiles = 4;
        cnt = 1 << 30;
        hbase = 2 * TNUM;
        n0 = nh * 1536 + ntl * 128;
        Bmat = Ws1t;
        bias = bs1;
    }
    if (mt0 >= ntiles) return;

    __shared__ __align__(16) unsigned short As[3][512 * 8];   // 3 x 8KB
    __shared__ __align__(16) unsigned short Bs[3][512 * 8];   // 3 x 8KB  (48KB total)

    int tid = threadIdx.x;
    int w = tid >> 6, lane = tid & 63;
    int l15 = lane & 15, quad = lane >> 4;
    int wm = (w & 1) * 64, wn = (w >> 1) * 64;

    const unsigned short* gB[2];
    int ldsoff[2];
    int rowl[2];
    #pragma unroll
    for (int r = 0; r < 2; r++) {
        int rc = r * 4 + w;
        rowl[r] = rc * 16 + l15;
        gB[r] = Bmat + (size_t)(n0 + rowl[r]) * DDIM + quad * 8;
        ldsoff[r] = rc * 512;
    }
    int rcA = (w & 1) * 4;
    int rcB = (w >> 1) * 4;
    const int KT = DDIM / 32;   // 24

    for (int mt = mt0; mt < ntiles; mt += 4) {
        int m0 = mbase + mt * 128;
        const unsigned short* gA[2];
        #pragma unroll
        for (int r = 0; r < 2; r++) {
            int row;
            if (lst) row = lst[min(m0 + rowl[r], cnt - 1)];
            else     row = m0 + rowl[r];
            gA[r] = xb + (size_t)row * DDIM + quad * 8;
        }

        f32x4 zero = {0.f, 0.f, 0.f, 0.f};
        f32x4 acc[4][4];
        #pragma unroll
        for (int i = 0; i < 4; i++)
            #pragma unroll
            for (int jj = 0; jj < 4; jj++) acc[i][jj] = zero;

        __builtin_amdgcn_s_barrier();       // prev mt's LDS readers done
        MEMFENCE();
        // prologue: tiles 0 and 1
        #pragma unroll
        for (int t = 0; t < 2; t++)
            #pragma unroll
            for (int r = 0; r < 2; r++) {
                async_cp16(gA[r] + t * 32, &As[t][ldsoff[r]]);
                async_cp16(gB[r] + t * 32, &Bs[t][ldsoff[r]]);
            }

        #pragma unroll 1
        for (int kt = 0; kt < KT; kt++) {
            if (kt == KT - 1) { WAITVM(0); } else { WAITVM(4); }   // tile kt arrived; kt+1 in flight
            __builtin_amdgcn_s_barrier();
            MEMFENCE();
            int cur = kt % 3;
            if (kt + 2 < KT) {
                int nb = (kt + 2) % 3;
                int ko = (kt + 2) * 32;
                #pragma unroll
                for (int r = 0; r < 2; r++) {
                    async_cp16(gA[r] + ko, &As[nb][ldsoff[r]]);
                    async_cp16(gB[r] + ko, &Bs[nb][ldsoff[r]]);
                }
            }
            bf16x8 af[4], bv[4];
            #pragma unroll
            for (int i = 0; i < 4; i++)
                af[i] = *(const bf16x8*)&As[cur][((rcA + i) * 64 + quad * 16 + l15) * 8];
            #pragma unroll
            for (int jj = 0; jj < 4; jj++)
                bv[jj] = *(const bf16x8*)&Bs[cur][((rcB + jj) * 64 + quad * 16 + l15) * 8];
            #pragma unroll
            for (int i = 0; i < 4; i++)
                #pragma unroll
                for (int jj = 0; jj < 4; jj++)
                    acc[i][jj] = __builtin_amdgcn_mfma_f32_16x16x32_bf16(af[i], bv[jj], acc[i][jj], 0, 0, 0);
        }

        #pragma unroll
        for (int i = 0; i < 4; i++) {
            int rbase = m0 + wm + i * 16 + quad * 4;
            #pragma unroll
            for (int jj = 0; jj < 4; jj++) {
                int gc = n0 + wn + jj * 16 + l15;
                float bvl = bias[gc];
                #pragma unroll
                for (int r = 0; r < 4; r++) {
                    int gr = rbase + r;
                    if (gr < cnt) {
                        float v = acc[i][jj][r] + bvl;
                        v = v > 0.f ? v : 0.01f * v;
                        hbuf[(size_t)(hbase + gr) * HDIM + gc] = f2bf(v);
                    }
                }
            }
        }
    }
}

// ---------------- GEMM layer 2: ybuf[kh] = h @ W2[e] (plain fp32 stores) ----------------
// BM=64, BN=128, BK=32, 3-buffer pipeline. 24 jobs:
//   j<16: expert e=j>>1, kh=j&1 (A 1.5MB + B-half 2.25MB in one XCD L2)
//   j>=16: shared (mh 0..3, kh)
__global__ __launch_bounds__(256, 4)
void ffn2_kernel(const unsigned short* __restrict__ hbuf,
                 const unsigned short* __restrict__ W2t,   // [8][768][3072]
                 const unsigned short* __restrict__ Ws2t,  // [768][3072]
                 const int* __restrict__ counts, const int* __restrict__ offs,
                 float* __restrict__ ybuf) {               // [2][6144][768]
    int j = blockIdx.z * 8 + blockIdx.x;    // 0..23
    int y = blockIdx.y;                     // 0..47
    int mt0 = y / 6, ntl = y % 6;           // mt0 0..7, ntl 0..5
    int cnt, hbase, mbase, kh, ntiles;
    const unsigned short* Bmat;
    if (j < 16) {
        int e = j >> 1; kh = j & 1;
        cnt = counts[e];
        ntiles = (cnt + 63) >> 6;
        mbase = 0;
        hbase = offs[e];
        Bmat = W2t + (size_t)e * DDIM * HDIM;
    } else {
        int q = j - 16;
        int mh = q >> 1; kh = q & 1;
        mbase = mh * 512;
        ntiles = 8;
        cnt = 1 << 30;
        hbase = 2 * TNUM;
        Bmat = Ws2t;
    }
    if (mt0 >= ntiles) return;
    int n0 = ntl * 128;
    int kbase = kh * (HDIM / 2);

    __shared__ __align__(16) unsigned short As[3][256 * 8];   // 3 x 4KB
    __shared__ __align__(16) unsigned short Bs[3][512 * 8];   // 3 x 8KB (36KB total)

    int tid = threadIdx.x;
    int w = tid >> 6, lane = tid & 63;
    int l15 = lane & 15, quad = lane >> 4;
    int wm = (w & 1) * 32, wn = (w >> 1) * 64;

    const unsigned short* gB[2];
    int ldsoffB[2];
    #pragma unroll
    for (int r = 0; r < 2; r++) {
        int rc = r * 4 + w;
        gB[r] = Bmat + (size_t)(n0 + rc * 16 + l15) * HDIM + kbase + quad * 8;
        ldsoffB[r] = rc * 512;
    }
    int rcA = (w & 1) * 2;
    int rcB = (w >> 1) * 4;
    const int KT = (HDIM / 2) / 32;   // 48
    int rowl = w * 16 + l15;
    float* yb = ybuf + (size_t)kh * 6144 * DDIM;

    for (int mt = mt0; mt < ntiles; mt += 8) {
        int m0 = mbase + mt * 64;
        int ra = (j < 16) ? min(m0 + rowl, cnt - 1) : (m0 + rowl);
        const unsigned short* gA0 = hbuf + (size_t)(hbase + ra) * HDIM + kbase + quad * 8;

        f32x4 zero = {0.f, 0.f, 0.f, 0.f};
        f32x4 acc[2][4];
        #pragma unroll
        for (int i = 0; i < 2; i++)
            #pragma unroll
            for (int jj = 0; jj < 4; jj++) acc[i][jj] = zero;

        __builtin_amdgcn_s_barrier();       // prev mt's LDS readers done
        MEMFENCE();
        #pragma unroll
        for (int t = 0; t < 2; t++) {
            async_cp16(gA0 + t * 32, &As[t][w * 512]);
            #pragma unroll
            for (int r = 0; r < 2; r++) async_cp16(gB[r] + t * 32, &Bs[t][ldsoffB[r]]);
        }

        #pragma unroll 1
        for (int kt = 0; kt < KT; kt++) {
            if (kt == KT - 1) { WAITVM(0); } else { WAITVM(3); }
            __builtin_amdgcn_s_barrier();
            MEMFENCE();
            int cur = kt % 3;
            if (kt + 2 < KT) {
                int nb = (kt + 2) % 3;
                int ko = (kt + 2) * 32;
                async_cp16(gA0 + ko, &As[nb][w * 512]);
                #pragma unroll
                for (int r = 0; r < 2; r++) async_cp16(gB[r] + ko, &Bs[nb][ldsoffB[r]]);
            }
            bf16x8 af[2], bv[4];
            #pragma unroll
            for (int i = 0; i < 2; i++)
                af[i] = *(const bf16x8*)&As[cur][((rcA + i) * 64 + quad * 16 + l15) * 8];
            #pragma unroll
            for (int jj = 0; jj < 4; jj++)
                bv[jj] = *(const bf16x8*)&Bs[cur][((rcB + jj) * 64 + quad * 16 + l15) * 8];
            #pragma unroll
            for (int i = 0; i < 2; i++)
                #pragma unroll
                for (int jj = 0; jj < 4; jj++)
                    acc[i][jj] = __builtin_amdgcn_mfma_f32_16x16x32_bf16(af[i], bv[jj], acc[i][jj], 0, 0, 0);
        }

        #pragma unroll
        for (int i = 0; i < 2; i++) {
            int rbase = m0 + wm + i * 16 + quad * 4;
            #pragma unroll
            for (int r = 0; r < 4; r++) {
                int gr = rbase + r;
                if (gr >= cnt) continue;
                float* orow = yb + (size_t)(hbase + gr) * DDIM + n0 + wn;
                #pragma unroll
                for (int jj = 0; jj < 4; jj++)
                    orow[jj * 16 + l15] = acc[i][jj][r];
            }
        }
    }
}

// ---------------- final mix: gather expert rows + shared, apply gates/biases ----------------
__global__ void mix_kernel(const float* __restrict__ ybuf, const int* __restrict__ inv,
                           const float* __restrict__ tokp, const int* __restrict__ offs,
                           const float* __restrict__ b2, const float* __restrict__ bs2,
                           const float* __restrict__ scal, float* __restrict__ out) {
    int t = blockIdx.x;
    int c = threadIdx.x * 4;          // blockDim = 192 -> covers 768
    int i0 = inv[t * 2 + 0], i1 = inv[t * 2 + 1];
    int e0 = i0 >> 16, sl0 = i0 & 0xFFFF;
    int e1 = i1 >> 16, sl1 = i1 & 0xFFFF;
    float p0 = tokp[t * 2 + 0], p1 = tokp[t * 2 + 1];
    float ws = scal[0], wmx = scal[1];
    size_t rA = (size_t)(offs[e0] + sl0) * DDIM + c;
    size_t rB = (size_t)(offs[e1] + sl1) * DDIM + c;
    size_t rS = (size_t)(2 * TNUM + t) * DDIM + c;
    const float* y0 = ybuf;
    const float* y1 = ybuf + (size_t)6144 * DDIM;
    float4 vA0 = *(const float4*)(y0 + rA);
    float4 vA1 = *(const float4*)(y1 + rA);
    float4 vB0 = *(const float4*)(y0 + rB);
    float4 vB1 = *(const float4*)(y1 + rB);
    float4 vS0 = *(const float4*)(y0 + rS);
    float4 vS1 = *(const float4*)(y1 + rS);
    float4 bA = *(const float4*)(b2 + e0 * DDIM + c);
    float4 bB = *(const float4*)(b2 + e1 * DDIM + c);
    float4 bS = *(const float4*)(bs2 + c);
    float4 o;
    o.x = ws * (vS0.x + vS1.x + bS.x) + wmx * (p0 * (vA0.x + vA1.x + bA.x) + p1 * (vB0.x + vB1.x + bB.x));
    o.y = ws * (vS0.y + vS1.y + bS.y) + wmx * (p0 * (vA0.y + vA1.y + bA.y) + p1 * (vB0.y + vB1.y + bB.y));
    o.z = ws * (vS0.z + vS1.z + bS.z) + wmx * (p0 * (vA0.z + vA1.z + bA.z) + p1 * (vB0.z + vB1.z + bB.z));
    o.w = ws * (vS0.w + vS1.w + bS.w) + wmx * (p0 * (vA0.w + vA1.w + bA.w) + p1 * (vB0.w + vB1.w + bB.w));
    *(float4*)(out + (size_t)t * DDIM + c) = o;
}

extern "C" void kernel_launch(void* const* d_in, const int* in_sizes, int n_in,
                              void* d_out, int out_size, void* d_ws, size_t ws_size,
                              hipStream_t stream) {
    const float* x     = (const float*)d_in[0];
    const float* noise = (const float*)d_in[1];
    const float* Wr    = (const float*)d_in[2];
    const float* br    = (const float*)d_in[3];
    const float* W1    = (const float*)d_in[4];
    const float* b1    = (const float*)d_in[5];
    const float* W2    = (const float*)d_in[6];
    const float* b2    = (const float*)d_in[7];
    const float* Ws1   = (const float*)d_in[8];
    const float* bs1   = (const float*)d_in[9];
    const float* Ws2   = (const float*)d_in[10];
    const float* bs2   = (const float*)d_in[11];
    const float* alpha = (const float*)d_in[12];
    const float* beta  = (const float*)d_in[13];

    char* ws = (char*)d_ws;
    size_t off = 0;
    auto alloc = [&](size_t bytes) -> char* {
        char* p = ws + off;
        off = (off + bytes + 255) & ~(size_t)255;
        return p;
    };
    int*   counts = (int*)  alloc(ENUM * 4);
    int*   offs   = (int*)  alloc(16 * 4);
    float* scal   = (float*)alloc(2 * 4);
    int*   list   = (int*)  alloc((size_t)ENUM * TNUM * 4);
    int*   inv    = (int*)  alloc((size_t)TNUM * 2 * 4);
    float* tokp   = (float*)alloc((size_t)TNUM * 2 * 4);
    unsigned short* xb   = (unsigned short*)alloc((size_t)TNUM * DDIM * 2);
    unsigned short* W1t  = (unsigned short*)alloc((size_t)ENUM * HDIM * DDIM * 2);  // 36 MB
    unsigned short* Ws1t = (unsigned short*)alloc((size_t)HDIM * DDIM * 2);         // 4.5 MB (adjacent)
    unsigned short* W2t  = (unsigned short*)alloc((size_t)ENUM * DDIM * HDIM * 2);
    unsigned short* Ws2t = (unsigned short*)alloc((size_t)DDIM * HDIM * 2);
    unsigned short* hbuf = (unsigned short*)alloc((size_t)(3 * TNUM) * HDIM * 2);
    // ybuf (2*6144*768*4 = 37.75 MB) aliases W1t+Ws1t (40.5 MB contiguous): last reader of
    // W1t/Ws1t is ffn1; ffn2 writes ybuf strictly after on the same stream.
    float* ybuf = (float*)W1t;
    if (off > ws_size) {
        fprintf(stderr, "kernel_launch: workspace too small (need %zu, have %zu)\n", off, ws_size);
        return;
    }

    hipMemsetAsync(counts, 0, ENUM * 4, stream);

    cast_x_kernel<<<dim3((TNUM * DDIM / 8) / 256), dim3(256), 0, stream>>>(x, xb);
    transw_kernel<<<dim3(144, 1, 18), dim3(256), 0, stream>>>(W1, W2, Ws1, Ws2, W1t, W2t, Ws1t, Ws2t);
    router_kernel<<<dim3(TNUM / 4), dim3(256), 0, stream>>>(x, noise, Wr, br, counts, list, inv, tokp);
    finalize_kernel<<<dim3(1), dim3(1), 0, stream>>>(counts, offs, alpha, beta, scal);
    // compact XCD-job grids: x = 8 (XCD slot), y = 48 tiles, z = job layer; mt-stride in-kernel
    ffn1_kernel<<<dim3(8, 48, 3), dim3(256), 0, stream>>>(xb, W1t, Ws1t, b1, bs1, counts, offs, list, hbuf);
    ffn2_kernel<<<dim3(8, 48, 3), dim3(256), 0, stream>>>(hbuf, W2t, Ws2t, counts, offs, ybuf);
    mix_kernel<<<dim3(TNUM), dim3(192), 0, stream>>>(ybuf, inv, tokp, offs, b2, bs2, scal, (float*)d_out);
}